// Round 1
// baseline (5336.959 us; speedup 1.0000x reference)
//
#include <hip/hip_runtime.h>

constexpr int NB = 128;   // batch
constexpr int NT = 512;   // time
constexpr int ND = 64;    // input dim
constexpr int NH = 512;   // hidden
constexpr int NL = 256;   // latent
constexpr int NG = 2048;  // 4*H

typedef _Float16 half8 __attribute__((ext_vector_type(8)));
typedef float F4 __attribute__((ext_vector_type(4)));

// ---------------- workspace layout (bytes) ----------------
constexpr size_t OFF_WFE = 0;                         // 2 MB  fragment-major W_hh_e fp16
constexpr size_t OFF_WFD = (2u << 20);                // 2 MB  fragment-major W_hh_d fp16
constexpr size_t OFF_WFX = (4u << 20);                // 256 KB fragment-major W_ih_e fp16
constexpr size_t OFF_XF  = (4u << 20) + (256u << 10); // 8 MB  x in A-fragment layout fp16
constexpr size_t OFF_HBE = OFF_XF + (8u << 20);       // 2 x 128 KB encoder h ping-pong (fp16, A-layout)
constexpr size_t OFF_HBD = OFF_HBE + (256u << 10);    // 2 x 128 KB decoder h ping-pong
constexpr size_t OFF_CB  = OFF_HBD + (256u << 10);    // 256 KB c state fp32 (block-private)
constexpr size_t OFF_YB  = OFF_CB + (256u << 10);     // 2 x 128 KB y ping-pong (fp16 row-major)
constexpr size_t OFF_Z   = OFF_YB + (256u << 10);     // 128 KB z fp32
constexpr size_t OFF_ZX  = OFF_Z + (128u << 10);      // 1 MB zx fp32
// total ~14.4 MB

__device__ inline float sigm(float x) {
  float e = __expf(-fabsf(x));
  float p = 1.f / (1.f + e);
  return x >= 0.f ? p : 1.f - p;
}
__device__ inline float tanh_(float x) {
  float e = __expf(-2.f * fabsf(x));
  float t = (1.f - e) / (1.f + e);
  return x >= 0.f ? t : -t;
}
__device__ inline half8 cvt8(F4 a, F4 b) {
  half8 h;
  h[0] = (_Float16)a[0]; h[1] = (_Float16)a[1]; h[2] = (_Float16)a[2]; h[3] = (_Float16)a[3];
  h[4] = (_Float16)b[0]; h[5] = (_Float16)b[1]; h[6] = (_Float16)b[2]; h[7] = (_Float16)b[3];
  return h;
}

// ------- setup: gather weights + x into fragment-major fp16 layouts -------
// WfE/WfD chunk idx = ((hc*4+g)*16+tt)*64 + l ; chunk = W[c][k8*8..+8], c=g*512+hc*16+(l&15), k8=4*tt+(l>>4)
// WfX chunk idx = ((hc*4+g)*2+tx)*64 + l
// Xf  chunk idx = ((t*8+bi)*8+k8)*16 + row ; chunk = x[bi*16+row][t][k8*8..+8]
__global__ __launch_bounds__(256) void setup_kernel(
    const float* __restrict__ x, const float* __restrict__ W_hh_e,
    const float* __restrict__ W_ih_e, const float* __restrict__ W_hh_d,
    half8* __restrict__ WfE, half8* __restrict__ WfX, half8* __restrict__ WfD,
    half8* __restrict__ Xf) {
  int c = blockIdx.x * 256 + threadIdx.x;
  if (c < 131072) {  // WfE
    int hc = c >> 12, g = (c >> 10) & 3, tt = (c >> 6) & 15, l = c & 63;
    int col = g * 512 + hc * 16 + (l & 15);
    int k8 = 4 * tt + (l >> 4);
    const F4* s = (const F4*)(W_hh_e + (size_t)col * 512 + k8 * 8);
    WfE[c] = cvt8(s[0], s[1]);
  } else if (c < 131072 + 16384) {  // WfX
    int id = c - 131072;
    int hc = id >> 9, g = (id >> 7) & 3, tx = (id >> 6) & 1, l = id & 63;
    int col = g * 512 + hc * 16 + (l & 15);
    int k8 = 4 * tx + (l >> 4);
    const F4* s = (const F4*)(W_ih_e + (size_t)col * 64 + k8 * 8);
    WfX[id] = cvt8(s[0], s[1]);
  } else if (c < 131072 + 16384 + 131072) {  // WfD
    int id = c - 147456;
    int hc = id >> 12, g = (id >> 10) & 3, tt = (id >> 6) & 15, l = id & 63;
    int col = g * 512 + hc * 16 + (l & 15);
    int k8 = 4 * tt + (l >> 4);
    const F4* s = (const F4*)(W_hh_d + (size_t)col * 512 + k8 * 8);
    WfD[id] = cvt8(s[0], s[1]);
  } else {  // Xf
    int id = c - 278528;
    int t = id >> 10, bi = (id >> 7) & 7, k8 = (id >> 4) & 7, row = id & 15;
    const F4* s = (const F4*)(x + ((size_t)(bi * 16 + row) * NT + t) * ND + k8 * 8);
    Xf[id] = cvt8(s[0], s[1]);
  }
}

// ------------------------- encoder step -------------------------
__global__ __launch_bounds__(256) void enc_step(
    const half8* __restrict__ Wf, const half8* __restrict__ Wfx,
    const half8* __restrict__ Xf, const _Float16* __restrict__ Hrd,
    _Float16* __restrict__ Hwr, float* __restrict__ Cbuf,
    const float* __restrict__ b_e, const int* __restrict__ lengths, int t) {
  int tid = threadIdx.x;
  int l = tid & 63, g = tid >> 6;
  int hc = (int)blockIdx.x & 31, bi = (int)blockIdx.x >> 5;
  __shared__ float gl[4][16][17];

  const half8* Ap = (const half8*)Hrd + bi * 1024 + l;
  const half8* Bp = Wf + ((hc * 4 + g) * 16) * 64 + l;
  F4 acc = {0.f, 0.f, 0.f, 0.f};
#pragma unroll
  for (int k = 0; k < 16; k++)
    acc = __builtin_amdgcn_mfma_f32_16x16x32_f16(Ap[64 * k], Bp[64 * k], acc, 0, 0, 0);
  const half8* Axp = Xf + ((size_t)t * 8 + bi) * 128 + l;
  const half8* Bxp = Wfx + ((hc * 4 + g) * 2) * 64 + l;
#pragma unroll
  for (int k = 0; k < 2; k++)
    acc = __builtin_amdgcn_mfma_f32_16x16x32_f16(Axp[64 * k], Bxp[64 * k], acc, 0, 0, 0);

  int r0 = (l >> 4) * 4;
#pragma unroll
  for (int r = 0; r < 4; r++) gl[g][r0 + r][l & 15] = acc[r];
  __syncthreads();

  int row = tid >> 4, col = tid & 15;
  int b = bi * 16 + row, hcol = hc * 16 + col;
  int len = lengths[b];
  size_t hidx = ((size_t)(bi * 64 + (hcol >> 3)) * 16 + row) * 8 + (hcol & 7);
  float hv;
  if (t < len) {
    float gi = gl[0][row][col] + b_e[hcol];
    float gf = gl[1][row][col] + b_e[512 + hcol];
    float gg = gl[2][row][col] + b_e[1024 + hcol];
    float go = gl[3][row][col] + b_e[1536 + hcol];
    float i = sigm(gi), f = sigm(gf), gz = tanh_(gg), o = sigm(go);
    float* cp = Cbuf + ((size_t)(bi * 32 + hc) * 16 + row) * 16 + col;
    float cn = f * (*cp) + i * gz;
    *cp = cn;
    hv = o * tanh_(cn);
  } else {
    hv = (float)Hrd[hidx];  // carry frozen state into write buffer
  }
  Hwr[hidx] = (_Float16)hv;
}

// ------------------------- z / zx -------------------------
__global__ __launch_bounds__(256) void z_kernel(const _Float16* __restrict__ Hfin,
                                                const float* __restrict__ W_lat,
                                                const float* __restrict__ b_lat,
                                                float* __restrict__ Z) {
  int b = blockIdx.x;        // 0..127
  int lc = threadIdx.x;      // 0..255
  int bi = b >> 4, row = b & 15;
  const half8* hp = (const half8*)Hfin + bi * 1024 + row;
  const F4* wp = (const F4*)(W_lat + (size_t)lc * 512);
  float acc = 0.f;
  for (int k8 = 0; k8 < 64; k8++) {
    half8 hv = hp[k8 * 16];
    F4 w0 = wp[2 * k8], w1 = wp[2 * k8 + 1];
    acc += (float)hv[0] * w0[0] + (float)hv[1] * w0[1] + (float)hv[2] * w0[2] + (float)hv[3] * w0[3]
         + (float)hv[4] * w1[0] + (float)hv[5] * w1[1] + (float)hv[6] * w1[2] + (float)hv[7] * w1[3];
  }
  Z[(size_t)b * 256 + lc] = acc + b_lat[lc];
}

__global__ __launch_bounds__(256) void zx_kernel(const float* __restrict__ Z,
                                                 const float* __restrict__ W_ihd,
                                                 const float* __restrict__ b_d,
                                                 float* __restrict__ ZX) {
  int o = blockIdx.x * 256 + threadIdx.x;  // grid 1024
  int b = o >> 11, gc = o & 2047;
  const F4* zp = (const F4*)(Z + (size_t)b * 256);
  const F4* wp = (const F4*)(W_ihd + (size_t)gc * 256);
  float acc = 0.f;
  for (int k4 = 0; k4 < 64; k4++) {
    F4 z = zp[k4], w = wp[k4];
    acc += z[0] * w[0] + z[1] * w[1] + z[2] * w[2] + z[3] * w[3];
  }
  ZX[o] = acc + b_d[gc];
}

// -------- output projection for one time column (device helper) --------
__device__ inline void outproj(const _Float16* __restrict__ Yprev,
                               const float* __restrict__ W_out,
                               const float* __restrict__ b_out,
                               float* __restrict__ out, int bi, int hc, int tid,
                               int tcol) {
  int s = tid & 7, idx = tid >> 3;  // 8-way k split, 32 (row,d) pairs
  int row = idx >> 1, dj = idx & 1, d = hc * 2 + dj;
  int b = bi * 16 + row;
  const half8* yp = (const half8*)(Yprev + (size_t)b * 512 + s * 64);
  const F4* wp = (const F4*)(W_out + (size_t)d * 512 + s * 64);
  float acc = 0.f;
#pragma unroll
  for (int k8 = 0; k8 < 8; k8++) {
    half8 yv = yp[k8];
    F4 w0 = wp[2 * k8], w1 = wp[2 * k8 + 1];
    acc += (float)yv[0] * w0[0] + (float)yv[1] * w0[1] + (float)yv[2] * w0[2] + (float)yv[3] * w0[3]
         + (float)yv[4] * w1[0] + (float)yv[5] * w1[1] + (float)yv[6] * w1[2] + (float)yv[7] * w1[3];
  }
  acc += __shfl_down(acc, 4, 8);
  acc += __shfl_down(acc, 2, 8);
  acc += __shfl_down(acc, 1, 8);
  if (s == 0) out[((size_t)b * NT + tcol) * ND + d] = acc + b_out[d];
}

// ------------------------- decoder step -------------------------
__global__ __launch_bounds__(256) void dec_step(
    const half8* __restrict__ Wf, const _Float16* __restrict__ Hrd,
    _Float16* __restrict__ Hwr, float* __restrict__ Cbuf,
    const float* __restrict__ zx, const _Float16* __restrict__ Yprev,
    _Float16* __restrict__ Ywr, const float* __restrict__ W_out,
    const float* __restrict__ b_out, float* __restrict__ out,
    const int* __restrict__ lengths, int t) {
  int tid = threadIdx.x;
  int l = tid & 63, g = tid >> 6;
  int hc = (int)blockIdx.x & 31, bi = (int)blockIdx.x >> 5;
  __shared__ float gl[4][16][17];

  if (t > 0) outproj(Yprev, W_out, b_out, out, bi, hc, tid, t - 1);

  const half8* Ap = (const half8*)Hrd + bi * 1024 + l;
  const half8* Bp = Wf + ((hc * 4 + g) * 16) * 64 + l;
  F4 acc = {0.f, 0.f, 0.f, 0.f};
#pragma unroll
  for (int k = 0; k < 16; k++)
    acc = __builtin_amdgcn_mfma_f32_16x16x32_f16(Ap[64 * k], Bp[64 * k], acc, 0, 0, 0);

  int r0 = (l >> 4) * 4;
#pragma unroll
  for (int r = 0; r < 4; r++) gl[g][r0 + r][l & 15] = acc[r];
  __syncthreads();

  int row = tid >> 4, col = tid & 15;
  int b = bi * 16 + row, hcol = hc * 16 + col;
  int len = lengths[b];
  size_t hidx = ((size_t)(bi * 64 + (hcol >> 3)) * 16 + row) * 8 + (hcol & 7);
  float hv, yv = 0.f;
  if (t < len) {
    const float* zr = zx + (size_t)b * 2048;
    float gi = gl[0][row][col] + zr[hcol];
    float gf = gl[1][row][col] + zr[512 + hcol];
    float gg = gl[2][row][col] + zr[1024 + hcol];
    float go = gl[3][row][col] + zr[1536 + hcol];
    float i = sigm(gi), f = sigm(gf), gz = tanh_(gg), o = sigm(go);
    float* cp = Cbuf + ((size_t)(bi * 32 + hc) * 16 + row) * 16 + col;
    float cn = f * (*cp) + i * gz;
    *cp = cn;
    hv = o * tanh_(cn);
    yv = hv;
  } else {
    hv = (float)Hrd[hidx];
  }
  Hwr[hidx] = (_Float16)hv;
  Ywr[(size_t)b * 512 + hcol] = (_Float16)yv;
}

__global__ __launch_bounds__(256) void dec_tail(const _Float16* __restrict__ Yprev,
                                                const float* __restrict__ W_out,
                                                const float* __restrict__ b_out,
                                                float* __restrict__ out) {
  int hc = (int)blockIdx.x & 31, bi = (int)blockIdx.x >> 5;
  outproj(Yprev, W_out, b_out, out, bi, hc, threadIdx.x, NT - 1);
}

// ------------------------- host -------------------------
extern "C" void kernel_launch(void* const* d_in, const int* in_sizes, int n_in,
                              void* d_out, int out_size, void* d_ws, size_t ws_size,
                              hipStream_t stream) {
  const float* x      = (const float*)d_in[0];
  const int* lengths  = (const int*)d_in[1];
  const float* W_ih_e = (const float*)d_in[2];
  const float* W_hh_e = (const float*)d_in[3];
  const float* b_e    = (const float*)d_in[4];
  const float* W_lat  = (const float*)d_in[5];
  const float* b_lat  = (const float*)d_in[6];
  const float* W_ih_d = (const float*)d_in[7];
  const float* W_hh_d = (const float*)d_in[8];
  const float* b_d    = (const float*)d_in[9];
  const float* W_out  = (const float*)d_in[10];
  const float* b_out  = (const float*)d_in[11];
  float* out = (float*)d_out;
  char* ws = (char*)d_ws;

  half8* WfE = (half8*)(ws + OFF_WFE);
  half8* WfD = (half8*)(ws + OFF_WFD);
  half8* WfX = (half8*)(ws + OFF_WFX);
  half8* Xf  = (half8*)(ws + OFF_XF);
  _Float16* HbE = (_Float16*)(ws + OFF_HBE);  // 2 x 65536 halves
  _Float16* HbD = (_Float16*)(ws + OFF_HBD);
  float* Cbuf = (float*)(ws + OFF_CB);
  _Float16* Yb = (_Float16*)(ws + OFF_YB);    // 2 x 65536 halves
  float* Z  = (float*)(ws + OFF_Z);
  float* ZX = (float*)(ws + OFF_ZX);

  hipMemsetAsync(HbE, 0, 128u << 10, stream);   // h0 = 0 (buf 0)
  hipMemsetAsync(Cbuf, 0, 256u << 10, stream);  // c0 = 0
  setup_kernel<<<3136, 256, 0, stream>>>(x, W_hh_e, W_ih_e, W_hh_d, WfE, WfX, WfD, Xf);

  for (int t = 0; t < NT; t++) {
    enc_step<<<256, 256, 0, stream>>>(WfE, WfX, Xf,
                                      HbE + (size_t)(t & 1) * 65536,
                                      HbE + (size_t)((t + 1) & 1) * 65536,
                                      Cbuf, b_e, lengths, t);
  }
  // final encoder h is in buf (NT & 1) == 0
  z_kernel<<<128, 256, 0, stream>>>(HbE, W_lat, b_lat, Z);
  zx_kernel<<<1024, 256, 0, stream>>>(Z, W_ih_d, b_d, ZX);

  hipMemsetAsync(HbD, 0, 128u << 10, stream);
  hipMemsetAsync(Cbuf, 0, 256u << 10, stream);

  for (int t = 0; t < NT; t++) {
    dec_step<<<256, 256, 0, stream>>>(WfD,
                                      HbD + (size_t)(t & 1) * 65536,
                                      HbD + (size_t)((t + 1) & 1) * 65536,
                                      Cbuf, ZX,
                                      Yb + (size_t)((t + 1) & 1) * 65536,  // Y[(t-1)&1]
                                      Yb + (size_t)(t & 1) * 65536,
                                      W_out, b_out, out, lengths, t);
  }
  dec_tail<<<256, 256, 0, stream>>>(Yb + 65536, W_out, b_out, out);  // t-1 = 511, buf 1
}